// Round 7
// baseline (201.610 us; speedup 1.0000x reference)
//
#include <hip/hip_runtime.h>

// q,k,v: [B=8, d=768, N=6144] fp32; head_dim=32, kernel_size=3
// h=24 heads, g=2048 windows; window elem j of window gg at n = j*2048 + gg
// out flat: [b][gg][hh][kq][dd] contiguous [8, 2048, 24, 3, 32]
//
// Round 7: contiguity-first design.
//  - Block = 256 threads = 4 waves, all sharing ONE 256-window span of one
//    (b,hh). Every global load: 64 lanes x float4 on the same (dd,j) row =
//    1KB contiguous per instruction, streamed row-by-row (vs 64-256B islands
//    in rounds 4-6 -- the ~2.9 TB/s service-rate wall was pattern-bound, not
//    occupancy-bound: 28%->77% occupancy moved BW not at all).
//  - dd is split across WAVES (not lanes): each wave redundantly computes all
//    scores (q,k re-read 4x within the block -> L1/L2 hits, HBM once), then
//    wave wv does PV + stores only for dd-octet wv*8..wv*8+7. No LDS, no
//    barriers, no cross-wave reduction.
//  - PV in 3 kq-passes keeps o[] at 32 regs (~100 VGPR); v re-reads across
//    passes hit L1. NO launch_bounds min-waves (round-6 spill lesson).
constexpr int CB = 8;
constexpr int CD = 768;
constexpr int CN = 6144;
constexpr int HD = 32;
constexpr int KS = 3;
constexpr int CH = CD / HD;       // 24
constexpr int CG = CN / KS;       // 2048
constexpr int GBLK = 256;         // windows per block
constexpr int NGB = CG / GBLK;    // 8 gg-blocks per (b,hh)
constexpr int OSTR = CH * KS * HD;  // 2304 floats per (b,gg) output block

__device__ __forceinline__ float c4(const float4& f, int w) {
  switch (w) { case 0: return f.x; case 1: return f.y; case 2: return f.z; default: return f.w; }
}

__global__ __launch_bounds__(256) void dilate_attn_kernel(
    const float* __restrict__ q, const float* __restrict__ k,
    const float* __restrict__ v, float* __restrict__ out) {
  const int bid  = blockIdx.x;
  const int gblk = bid & (NGB - 1);
  const int bh   = bid >> 3;          // b*24 + hh
  const int hh   = bh % CH;
  const int b    = bh / CH;
  const int wv   = threadIdx.x >> 6;  // wave id = dd-octet owner for PV/store
  const int lane = threadIdx.x & 63;

  const int gg0 = gblk * GBLK + lane * 4;   // 4 consecutive windows per thread

  const size_t base = ((size_t)(b * CD + hh * HD)) * (size_t)CN + (size_t)gg0;
  const float* qb = q + base;
  const float* kb = k + base;

  // ---- scores sc[w][kq][kj], all 32 dd (redundant across the 4 waves)
  float sc[4][3][3];
  #pragma unroll
  for (int w = 0; w < 4; ++w)
    #pragma unroll
    for (int a = 0; a < 3; ++a)
      #pragma unroll
      for (int c = 0; c < 3; ++c) sc[w][a][c] = 0.f;

  #pragma unroll 8
  for (int dd = 0; dd < HD; ++dd) {
    const float* qr = qb + (size_t)dd * CN;
    const float* kr = kb + (size_t)dd * CN;
    const float4 qa0 = *reinterpret_cast<const float4*>(qr);
    const float4 qa1 = *reinterpret_cast<const float4*>(qr + CG);
    const float4 qa2 = *reinterpret_cast<const float4*>(qr + 2 * CG);
    const float4 kc0 = *reinterpret_cast<const float4*>(kr);
    const float4 kc1 = *reinterpret_cast<const float4*>(kr + CG);
    const float4 kc2 = *reinterpret_cast<const float4*>(kr + 2 * CG);
    #pragma unroll
    for (int w = 0; w < 4; ++w) {
      const float q0 = c4(qa0, w), q1 = c4(qa1, w), q2 = c4(qa2, w);
      const float k0 = c4(kc0, w), k1 = c4(kc1, w), k2 = c4(kc2, w);
      sc[w][0][0] = fmaf(q0, k0, sc[w][0][0]);
      sc[w][0][1] = fmaf(q0, k1, sc[w][0][1]);
      sc[w][0][2] = fmaf(q0, k2, sc[w][0][2]);
      sc[w][1][0] = fmaf(q1, k0, sc[w][1][0]);
      sc[w][1][1] = fmaf(q1, k1, sc[w][1][1]);
      sc[w][1][2] = fmaf(q1, k2, sc[w][1][2]);
      sc[w][2][0] = fmaf(q2, k0, sc[w][2][0]);
      sc[w][2][1] = fmaf(q2, k1, sc[w][2][1]);
      sc[w][2][2] = fmaf(q2, k2, sc[w][2][2]);
    }
  }

  // ---- softmax over kj per (w, kq)
  const float scale = 0.17677669529663687f;  // 32^-0.5
  float p[4][3][3];
  #pragma unroll
  for (int w = 0; w < 4; ++w) {
    #pragma unroll
    for (int a = 0; a < 3; ++a) {
      const float x0 = sc[w][a][0] * scale;
      const float x1 = sc[w][a][1] * scale;
      const float x2 = sc[w][a][2] * scale;
      const float m  = fmaxf(fmaxf(x0, x1), x2);
      const float e0 = __expf(x0 - m), e1 = __expf(x1 - m), e2 = __expf(x2 - m);
      const float r  = 1.f / (e0 + e1 + e2);
      p[w][a][0] = e0 * r; p[w][a][1] = e1 * r; p[w][a][2] = e2 * r;
    }
  }

  // ---- PV + store for this wave's dd-octet, 3 kq-passes (o stays 32 regs)
  const float* vb = v + ((size_t)(b * CD + hh * HD + wv * 8)) * (size_t)CN + (size_t)gg0;
  const size_t ob0 = (size_t)(b * CG + gg0) * (size_t)OSTR
                   + (size_t)hh * (KS * HD) + (size_t)(wv * 8);

  #pragma unroll
  for (int a = 0; a < 3; ++a) {
    float o[4][8];
    #pragma unroll
    for (int d = 0; d < 8; ++d) {
      const float* vr = vb + (size_t)d * CN;
      const float4 v0 = *reinterpret_cast<const float4*>(vr);
      const float4 v1 = *reinterpret_cast<const float4*>(vr + CG);
      const float4 v2 = *reinterpret_cast<const float4*>(vr + 2 * CG);
      #pragma unroll
      for (int w = 0; w < 4; ++w)
        o[w][d] = fmaf(p[w][a][0], c4(v0, w),
                  fmaf(p[w][a][1], c4(v1, w), p[w][a][2] * c4(v2, w)));
    }
    #pragma unroll
    for (int w = 0; w < 4; ++w) {
      float* op = out + ob0 + (size_t)w * OSTR + (size_t)(a * HD);
      *reinterpret_cast<float4*>(op)     = make_float4(o[w][0], o[w][1], o[w][2], o[w][3]);
      *reinterpret_cast<float4*>(op + 4) = make_float4(o[w][4], o[w][5], o[w][6], o[w][7]);
    }
  }
}

extern "C" void kernel_launch(void* const* d_in, const int* in_sizes, int n_in,
                              void* d_out, int out_size, void* d_ws, size_t ws_size,
                              hipStream_t stream) {
  const float* q = (const float*)d_in[0];
  const float* k = (const float*)d_in[1];
  const float* v = (const float*)d_in[2];
  float* out = (float*)d_out;

  const int blocks = CB * CH * NGB;   // 8*24*8 = 1536 blocks (6/CU), 256 thr
  dilate_attn_kernel<<<blocks, 256, 0, stream>>>(q, k, v, out);
}

// Round 8
// 128.255 us; speedup vs baseline: 1.5720x; 1.5720x over previous
//
#include <hip/hip_runtime.h>
#include <stdint.h>

// q,k,v: [B=8, d=768, N=6144] fp32; head_dim=32, kernel_size=3
// h=24 heads, g=2048 windows; window elem j of window gg at n = j*2048 + gg
// out flat: [b][gg][hh][kq][dd] contiguous [8, 2048, 24, 3, 32]
//
// Round 8: round-6 structure, VGPR-honest (<64 target, no forced min-waves).
//  - 4 threads per window: lane = slice*16 + wl; slice owns dd-octet.
//  - partial scores over own 8 dd, combined with shfl_xor(16)+shfl_xor(32);
//    softmax redundant per slice (in-place, reuses score regs).
//  - v preloaded into 24 regs BEFORE the shuffle+softmax VALU phase (latency
//    hidden); PV register-only, row-by-row, stores issued immediately.
//  - ALL global addressing via 32-bit element offsets from SGPR base pointers
//    (37.7M elements < 2^31) -> saddr+voffset loads, saves 64-bit addr pairs.
//  - 24576 waves supplied; at <=64 VGPR the HW allows 8 waves/SIMD.
constexpr int CB = 8;
constexpr int CD = 768;
constexpr int CN = 6144;
constexpr int HD = 32;
constexpr int KS = 3;
constexpr int CH = CD / HD;   // 24
constexpr int CG = CN / KS;   // 2048

__global__ __launch_bounds__(256) void dilate_attn_kernel(
    const float* __restrict__ q, const float* __restrict__ k,
    const float* __restrict__ v, float* __restrict__ out) {
  const int tid   = blockIdx.x * 256 + threadIdx.x;
  const int lane  = threadIdx.x & 63;
  const int wav   = tid >> 6;              // 0..24575
  const int slice = lane >> 4;             // dd-octet owner
  const int wl    = lane & 15;             // window within wave
  const int gg    = (wav & 127) * 16 + wl; // 128 waves per (b,hh)
  const int bh    = wav >> 7;              // b*24 + hh
  const int hh    = bh % CH;
  const int b     = bh / CH;

  // 32-bit element offset of row dd = hh*32 + slice*8, window-elem j=0, col gg
  const uint32_t inoff = (uint32_t)(b * CD + hh * HD + slice * 8) * (uint32_t)CN
                       + (uint32_t)gg;

  // ---- partial scores over this slice's 8 dd (one 48-load batch)
  float s00 = 0.f, s01 = 0.f, s02 = 0.f;
  float s10 = 0.f, s11 = 0.f, s12 = 0.f;
  float s20 = 0.f, s21 = 0.f, s22 = 0.f;
  #pragma unroll
  for (int d = 0; d < 8; ++d) {
    const uint32_t o = inoff + (uint32_t)d * CN;
    const float q0 = q[o], q1 = q[o + CG], q2 = q[o + 2 * CG];
    const float k0 = k[o], k1 = k[o + CG], k2 = k[o + 2 * CG];
    s00 = fmaf(q0, k0, s00); s01 = fmaf(q0, k1, s01); s02 = fmaf(q0, k2, s02);
    s10 = fmaf(q1, k0, s10); s11 = fmaf(q1, k1, s11); s12 = fmaf(q1, k2, s12);
    s20 = fmaf(q2, k0, s20); s21 = fmaf(q2, k1, s21); s22 = fmaf(q2, k2, s22);
  }

  // ---- issue v loads now; latency hides under shuffles + softmax
  float va[8], vb[8], vc[8];
  #pragma unroll
  for (int d = 0; d < 8; ++d) {
    const uint32_t o = inoff + (uint32_t)d * CN;
    va[d] = v[o]; vb[d] = v[o + CG]; vc[d] = v[o + 2 * CG];
  }

  // ---- combine partial scores across the 4 slices (lane^16, lane^32)
  s00 += __shfl_xor(s00, 16); s01 += __shfl_xor(s01, 16); s02 += __shfl_xor(s02, 16);
  s10 += __shfl_xor(s10, 16); s11 += __shfl_xor(s11, 16); s12 += __shfl_xor(s12, 16);
  s20 += __shfl_xor(s20, 16); s21 += __shfl_xor(s21, 16); s22 += __shfl_xor(s22, 16);
  s00 += __shfl_xor(s00, 32); s01 += __shfl_xor(s01, 32); s02 += __shfl_xor(s02, 32);
  s10 += __shfl_xor(s10, 32); s11 += __shfl_xor(s11, 32); s12 += __shfl_xor(s12, 32);
  s20 += __shfl_xor(s20, 32); s21 += __shfl_xor(s21, 32); s22 += __shfl_xor(s22, 32);

  // ---- softmax over kj, per row kq (in-place; redundant in all 4 slices)
  const float scale = 0.17677669529663687f;  // 32^-0.5
  {
    const float x0 = s00 * scale, x1 = s01 * scale, x2 = s02 * scale;
    const float m = fmaxf(fmaxf(x0, x1), x2);
    const float e0 = __expf(x0 - m), e1 = __expf(x1 - m), e2 = __expf(x2 - m);
    const float r = 1.f / (e0 + e1 + e2);
    s00 = e0 * r; s01 = e1 * r; s02 = e2 * r;
  }
  {
    const float x0 = s10 * scale, x1 = s11 * scale, x2 = s12 * scale;
    const float m = fmaxf(fmaxf(x0, x1), x2);
    const float e0 = __expf(x0 - m), e1 = __expf(x1 - m), e2 = __expf(x2 - m);
    const float r = 1.f / (e0 + e1 + e2);
    s10 = e0 * r; s11 = e1 * r; s12 = e2 * r;
  }
  {
    const float x0 = s20 * scale, x1 = s21 * scale, x2 = s22 * scale;
    const float m = fmaxf(fmaxf(x0, x1), x2);
    const float e0 = __expf(x0 - m), e1 = __expf(x1 - m), e2 = __expf(x2 - m);
    const float r = 1.f / (e0 + e1 + e2);
    s20 = e0 * r; s21 = e1 * r; s22 = e2 * r;
  }

  // ---- PV from registers, row-by-row, immediate stores.
  // out offset (32-bit): (b*CG+gg)*2304 + hh*96 + kq*32 + slice*8
  const uint32_t ooff = (uint32_t)(b * CG + gg) * (uint32_t)(CH * KS * HD)
                      + (uint32_t)(hh * KS * HD) + (uint32_t)(slice * 8);

  float o0, o1, o2, o3, o4, o5, o6, o7;
  // kq = 0
  o0 = fmaf(s00, va[0], fmaf(s01, vb[0], s02 * vc[0]));
  o1 = fmaf(s00, va[1], fmaf(s01, vb[1], s02 * vc[1]));
  o2 = fmaf(s00, va[2], fmaf(s01, vb[2], s02 * vc[2]));
  o3 = fmaf(s00, va[3], fmaf(s01, vb[3], s02 * vc[3]));
  o4 = fmaf(s00, va[4], fmaf(s01, vb[4], s02 * vc[4]));
  o5 = fmaf(s00, va[5], fmaf(s01, vb[5], s02 * vc[5]));
  o6 = fmaf(s00, va[6], fmaf(s01, vb[6], s02 * vc[6]));
  o7 = fmaf(s00, va[7], fmaf(s01, vb[7], s02 * vc[7]));
  *reinterpret_cast<float4*>(out + ooff + 0 * HD)     = make_float4(o0, o1, o2, o3);
  *reinterpret_cast<float4*>(out + ooff + 0 * HD + 4) = make_float4(o4, o5, o6, o7);
  // kq = 1
  o0 = fmaf(s10, va[0], fmaf(s11, vb[0], s12 * vc[0]));
  o1 = fmaf(s10, va[1], fmaf(s11, vb[1], s12 * vc[1]));
  o2 = fmaf(s10, va[2], fmaf(s11, vb[2], s12 * vc[2]));
  o3 = fmaf(s10, va[3], fmaf(s11, vb[3], s12 * vc[3]));
  o4 = fmaf(s10, va[4], fmaf(s11, vb[4], s12 * vc[4]));
  o5 = fmaf(s10, va[5], fmaf(s11, vb[5], s12 * vc[5]));
  o6 = fmaf(s10, va[6], fmaf(s11, vb[6], s12 * vc[6]));
  o7 = fmaf(s10, va[7], fmaf(s11, vb[7], s12 * vc[7]));
  *reinterpret_cast<float4*>(out + ooff + 1 * HD)     = make_float4(o0, o1, o2, o3);
  *reinterpret_cast<float4*>(out + ooff + 1 * HD + 4) = make_float4(o4, o5, o6, o7);
  // kq = 2
  o0 = fmaf(s20, va[0], fmaf(s21, vb[0], s22 * vc[0]));
  o1 = fmaf(s20, va[1], fmaf(s21, vb[1], s22 * vc[1]));
  o2 = fmaf(s20, va[2], fmaf(s21, vb[2], s22 * vc[2]));
  o3 = fmaf(s20, va[3], fmaf(s21, vb[3], s22 * vc[3]));
  o4 = fmaf(s20, va[4], fmaf(s21, vb[4], s22 * vc[4]));
  o5 = fmaf(s20, va[5], fmaf(s21, vb[5], s22 * vc[5]));
  o6 = fmaf(s20, va[6], fmaf(s21, vb[6], s22 * vc[6]));
  o7 = fmaf(s20, va[7], fmaf(s21, vb[7], s22 * vc[7]));
  *reinterpret_cast<float4*>(out + ooff + 2 * HD)     = make_float4(o0, o1, o2, o3);
  *reinterpret_cast<float4*>(out + ooff + 2 * HD + 4) = make_float4(o4, o5, o6, o7);
}

extern "C" void kernel_launch(void* const* d_in, const int* in_sizes, int n_in,
                              void* d_out, int out_size, void* d_ws, size_t ws_size,
                              hipStream_t stream) {
  const float* q = (const float*)d_in[0];
  const float* k = (const float*)d_in[1];
  const float* v = (const float*)d_in[2];
  float* out = (float*)d_out;

  const int total = CB * CH * CG * 4;   // 1572864 threads, 4 per window
  const int blocks = total / 256;       // 6144 blocks = 24576 waves
  dilate_attn_kernel<<<blocks, 256, 0, stream>>>(q, k, v, out);
}